// Round 6
// baseline (329.407 us; speedup 1.0000x reference)
//
#include <hip/hip_runtime.h>
#include <hip/hip_bf16.h>

// Problem constants (from reference)
#define N0 409600
#define N1 40960
#define N2 4096
#define E1c 409600
#define E2c 40960
#define F_IN 512
#define F_HID 256
#define F_OUT 128

using bf16x8 = __attribute__((ext_vector_type(8))) short;
using f32x4  = __attribute__((ext_vector_type(4))) float;

__device__ __forceinline__ ushort f2bf(float f) {
    union { float f; unsigned u; } v; v.f = f;
    unsigned r = v.u + 0x7fffu + ((v.u >> 16) & 1u);
    return (ushort)(r >> 16);
}
__device__ __forceinline__ float bf2f(ushort b) {
    union { unsigned u; float f; } v; v.u = ((unsigned)b) << 16;
    return v.f;
}

// ---- gather-accumulate one source row (f32: 8 feats/lane, bf16: 4 feats/lane) ----
__device__ __forceinline__ void acc_row(const float* rowp, int lane, float* a) {
    const float4* q = (const float4*)rowp + lane * 2;
    float4 u = q[0], v = q[1];
    a[0] += u.x; a[1] += u.y; a[2] += u.z; a[3] += u.w;
    a[4] += v.x; a[5] += v.y; a[6] += v.z; a[7] += v.w;
}
__device__ __forceinline__ void acc_row(const ushort* rowp, int lane, float* a) {
    ushort4 u = ((const ushort4*)rowp)[lane];
    a[0] += bf2f(u.x); a[1] += bf2f(u.y); a[2] += bf2f(u.z); a[3] += bf2f(u.w);
}
// ---- stage 4 A2 elements into LDS (convert f32->bf16 or copy bf16) ----
__device__ __forceinline__ void stage_ax(const float* g, ushort* l) {
    float4 v = *(const float4*)g;
    ushort4 o;
    o.x = f2bf(v.x); o.y = f2bf(v.y); o.z = f2bf(v.z); o.w = f2bf(v.w);
    *(ushort4*)l = o;
}
__device__ __forceinline__ void stage_ax(const ushort* g, ushort* l) {
    *(ushort4*)l = *(const ushort4*)g;
}

// ---------------- fused: histogram (both layers) + weight transpose/convert ----------------
__global__ void k_prep(const int* __restrict__ dst1, int* __restrict__ cnt1,
                       const int* __restrict__ dst2, int* __restrict__ cnt2,
                       const float* __restrict__ W1l, const float* __restrict__ W1r,
                       const float* __restrict__ W2l, const float* __restrict__ W2r,
                       ushort* __restrict__ W1lT, ushort* __restrict__ W1rT,
                       ushort* __restrict__ W2lT, ushort* __restrict__ W2rT) {
    int idx = blockIdx.x * blockDim.x + threadIdx.x;
    if (idx < E1c) atomicAdd(&cnt1[dst1[idx]], 1);
    else if (idx - E1c < E2c) atomicAdd(&cnt2[dst2[idx - E1c]], 1);
    const int S1 = F_IN * F_HID;
    const int S2 = F_HID * F_OUT;
    if (idx < S1) {
        int k = idx / F_HID, n = idx % F_HID;
        W1lT[(size_t)n * F_IN + k] = f2bf(W1l[idx]);
    } else if (idx < 2 * S1) {
        int j = idx - S1;
        int k = j / F_HID, n = j % F_HID;
        W1rT[(size_t)n * F_IN + k] = f2bf(W1r[j]);
    } else if (idx < 2 * S1 + S2) {
        int j = idx - 2 * S1;
        int k = j / F_OUT, n = j % F_OUT;
        W2lT[(size_t)n * F_HID + k] = f2bf(W2l[j]);
    } else if (idx < 2 * S1 + 2 * S2) {
        int j = idx - 2 * S1 - S2;
        int k = j / F_OUT, n = j % F_OUT;
        W2rT[(size_t)n * F_HID + k] = f2bf(W2r[j]);
    }
}

#define NBLK1 (N1 / 1024)   // 40
#define NBLK2 (N2 / 1024)   // 4

// ---------------- scan phase A (both layers in one grid) ----------------
__global__ __launch_bounds__(1024) void k_scanA2(const int* __restrict__ cnt1, int* __restrict__ off1,
                                                 int* __restrict__ bsum1,
                                                 const int* __restrict__ cnt2, int* __restrict__ off2,
                                                 int* __restrict__ bsum2) {
    __shared__ int wsum[16];
    int blk = blockIdx.x;
    const int* cnt; int* off; int* bsum; int lb;
    if (blk < NBLK1) { cnt = cnt1; off = off1; bsum = bsum1; lb = blk; }
    else             { cnt = cnt2; off = off2; bsum = bsum2; lb = blk - NBLK1; }
    int t = threadIdx.x, lane = t & 63, w = t >> 6;
    int i = lb * 1024 + t;
    int v = cnt[i];
    int s = v;
#pragma unroll
    for (int d = 1; d < 64; d <<= 1) {
        int u = __shfl_up(s, d, 64);
        if (lane >= d) s += u;
    }
    if (lane == 63) wsum[w] = s;
    __syncthreads();
    int wpre = 0, total = 0;
#pragma unroll
    for (int j = 0; j < 16; j++) {
        int u = wsum[j];
        if (j < w) wpre += u;
        total += u;
    }
    off[i] = wpre + (s - v);
    if (t == 0) bsum[lb] = total;
}

// ---------------- scan phase B ----------------
__global__ __launch_bounds__(1024) void k_scanB2(int* __restrict__ off1, int* __restrict__ cur1,
                                                 const int* __restrict__ bsum1,
                                                 int* __restrict__ off2, int* __restrict__ cur2,
                                                 const int* __restrict__ bsum2) {
    __shared__ int s_pre, s_tot;
    int blk = blockIdx.x;
    int* off; int* cur; const int* bsum; int lb, nblk, n;
    if (blk < NBLK1) { off = off1; cur = cur1; bsum = bsum1; lb = blk;         nblk = NBLK1; n = N1; }
    else             { off = off2; cur = cur2; bsum = bsum2; lb = blk - NBLK1; nblk = NBLK2; n = N2; }
    int t = threadIdx.x;
    if (t < 64) {
        int v = (t < nblk) ? bsum[t] : 0;
        int p = (t < lb) ? v : 0;
        int tt = v;
#pragma unroll
        for (int d = 32; d >= 1; d >>= 1) {
            p  += __shfl_xor(p, d, 64);
            tt += __shfl_xor(tt, d, 64);
        }
        if (t == 0) { s_pre = p; s_tot = tt; }
    }
    __syncthreads();
    int i = lb * 1024 + t;
    int val = off[i] + s_pre;
    off[i] = val;
    cur[i] = val;
    if (lb == 0 && t == 0) off[n] = s_tot;
}

// ---------------- fused scatter (both layers) ----------------
__global__ void k_scatter2(const int* __restrict__ src1, const int* __restrict__ dst1,
                           int* __restrict__ cur1, int* __restrict__ perm1,
                           const int* __restrict__ src2, const int* __restrict__ dst2,
                           int* __restrict__ cur2, int* __restrict__ perm2) {
    int e = blockIdx.x * blockDim.x + threadIdx.x;
    if (e < E1c) {
        int d = dst1[e];
        int pos = atomicAdd(&cur1[d], 1);
        perm1[pos] = src1[e];
    } else {
        int e2 = e - E1c;
        if (e2 < E2c) {
            int d = dst2[e2];
            int pos = atomicAdd(&cur2[d], 1);
            perm2[pos] = src2[e2];
        }
    }
}

// ---------------- fused SAGE layer: gather-mean into LDS, then dual MFMA GEMM ----------------
// out = act( mean(src[neigh]) @ BlT^T + src[:M] @ BrT^T + bias )
// src: [N_src][K] (f32 layer1, bf16 layer2). BlT,BrT: [BN][K] bf16 (pre-transposed).
// Block = 256 threads (4 waves), owns 32 output rows. Grid.x = M/32. BN = full N.
template<int BN, int K, int WN, typename TSRC, bool RELU, bool OUTF32>
__global__ __launch_bounds__(256) void k_sage(
    const TSRC* __restrict__ src,
    const int* __restrict__ perm, const int* __restrict__ off,
    const ushort* __restrict__ BlT, const ushort* __restrict__ BrT,
    const float* __restrict__ bias,
    ushort* __restrict__ outb, float* __restrict__ outf)
{
    constexpr int WM = 4 / WN;           // wave grid WM x WN
    constexpr int MF = 2 / WM;           // 16-row frags per wave (BM=32)
    constexpr int NF = BN / (WN * 16);   // 16-col frags per wave
    constexpr int FPL = (sizeof(TSRC) == 4) ? 8 : 4;  // features per lane in gather

    __shared__ ushort Am[32][K + 8];     // mean tile (bf16), persistent
    __shared__ ushort Bs[BN][40];        // B panel per K-step
    __shared__ ushort Ax[32][40];        // A2 (src[:M]) per K-step

    int tid = threadIdx.x;
    int lane = tid & 63;
    int w = tid >> 6;
    int bm = blockIdx.x * 32;

    // ---- phase 1: gather + mean, 8 rows per wave ----
    for (int rr = 0; rr < 8; rr++) {
        int row = w * 8 + rr;
        int d = bm + row;
        int beg = off[d], end = off[d + 1];
        float a[FPL];
#pragma unroll
        for (int j = 0; j < FPL; j++) a[j] = 0.f;
        int e = beg;
        for (; e + 3 < end; e += 4) {
            int s0 = perm[e], s1 = perm[e + 1], s2 = perm[e + 2], s3 = perm[e + 3];
            acc_row(src + (size_t)s0 * K, lane, a);
            acc_row(src + (size_t)s1 * K, lane, a);
            acc_row(src + (size_t)s2 * K, lane, a);
            acc_row(src + (size_t)s3 * K, lane, a);
        }
        for (; e < end; e++) acc_row(src + (size_t)perm[e] * K, lane, a);
        int deg = end - beg;
        float inv = 1.0f / (float)(deg > 0 ? deg : 1);
        if constexpr (FPL == 8) {
            bf16x8 o;
#pragma unroll
            for (int j = 0; j < 8; j++) o[j] = (short)f2bf(a[j] * inv);
            *(bf16x8*)&Am[row][lane * 8] = o;
        } else {
            ushort4 o;
            o.x = f2bf(a[0] * inv); o.y = f2bf(a[1] * inv);
            o.z = f2bf(a[2] * inv); o.w = f2bf(a[3] * inv);
            *(ushort4*)&Am[row][lane * 4] = o;
        }
    }
    __syncthreads();

    // ---- phase 2: dual GEMM over K ----
    int wm = w / WN, wn = w % WN;
    int sr = tid >> 2, sc = (tid & 3) * 8;
    int r0 = lane & 15, kq = (lane >> 4) * 8;
    f32x4 acc[MF][NF];
#pragma unroll
    for (int i = 0; i < MF; i++)
#pragma unroll
        for (int j = 0; j < NF; j++) acc[i][j] = (f32x4){0.f, 0.f, 0.f, 0.f};

#pragma unroll 1
    for (int part = 0; part < 2; ++part) {
        const ushort* __restrict__ B = part ? BrT : BlT;
        for (int k0 = 0; k0 < K; k0 += 32) {
#pragma unroll
            for (int i = 0; i < BN / 64; i++)
                *(bf16x8*)&Bs[sr + i * 64][sc] =
                    *(const bf16x8*)&B[(size_t)(sr + i * 64) * K + k0 + sc];
            if (part) {
                int r = tid >> 3, c = (tid & 7) * 4;
                stage_ax(src + (size_t)(bm + r) * K + k0 + c, &Ax[r][c]);
            }
            __syncthreads();
            bf16x8 af[MF], bfr[NF];
#pragma unroll
            for (int i = 0; i < MF; i++)
                af[i] = part ? *(const bf16x8*)&Ax[wm * (MF * 16) + i * 16 + r0][kq]
                             : *(const bf16x8*)&Am[wm * (MF * 16) + i * 16 + r0][k0 + kq];
#pragma unroll
            for (int j = 0; j < NF; j++)
                bfr[j] = *(const bf16x8*)&Bs[wn * (NF * 16) + j * 16 + r0][kq];
#pragma unroll
            for (int i = 0; i < MF; i++)
#pragma unroll
                for (int j = 0; j < NF; j++)
                    acc[i][j] = __builtin_amdgcn_mfma_f32_16x16x32_bf16(af[i], bfr[j], acc[i][j], 0, 0, 0);
            __syncthreads();
        }
    }

    // ---- epilogue: C/D layout col = lane&15, row = (lane>>4)*4 + reg ----
    int cn0 = lane & 15;
    int rq = (lane >> 4) * 4;
#pragma unroll
    for (int i = 0; i < MF; i++) {
#pragma unroll
        for (int j = 0; j < NF; j++) {
            int col = wn * (NF * 16) + j * 16 + cn0;
            float bv = bias[col];
#pragma unroll
            for (int rr = 0; rr < 4; rr++) {
                int row = bm + wm * (MF * 16) + i * 16 + rq + rr;
                float v = acc[i][j][rr] + bv;
                if (RELU) v = fmaxf(v, 0.f);
                if (OUTF32) outf[(size_t)row * BN + col] = v;
                else        outb[(size_t)row * BN + col] = f2bf(v);
            }
        }
    }
}

static inline size_t align256(size_t x) { return (x + 255) & ~(size_t)255; }

extern "C" void kernel_launch(void* const* d_in, const int* in_sizes, int n_in,
                              void* d_out, int out_size, void* d_ws, size_t ws_size,
                              hipStream_t stream) {
    const float* x = (const float*)d_in[0];
    const int* ei1_src = (const int*)d_in[1];
    const int* ei1_dst = (const int*)d_in[2];
    const int* ei2_src = (const int*)d_in[3];
    const int* ei2_dst = (const int*)d_in[4];
    const float* W1l = (const float*)d_in[5];
    const float* b1 = (const float*)d_in[6];
    const float* W1r = (const float*)d_in[7];
    const float* W2l = (const float*)d_in[8];
    const float* b2 = (const float*)d_in[9];
    const float* W2r = (const float*)d_in[10];
    float* out = (float*)d_out;

    // workspace layout (cnt1+cnt2 contiguous for a single memset)
    char* p = (char*)d_ws;
    size_t o = 0;
    int* cnt1 = (int*)(p + o); o += (size_t)N1 * 4;
    int* cnt2 = (int*)(p + o); o = align256(o + (size_t)N2 * 4);
    int* off1 = (int*)(p + o); o = align256(o + (size_t)(N1 + 1) * 4);
    int* cur1 = (int*)(p + o); o = align256(o + (size_t)N1 * 4);
    int* perm1 = (int*)(p + o); o = align256(o + (size_t)E1c * 4);
    int* off2 = (int*)(p + o); o = align256(o + (size_t)(N2 + 1) * 4);
    int* cur2 = (int*)(p + o); o = align256(o + (size_t)N2 * 4);
    int* perm2 = (int*)(p + o); o = align256(o + (size_t)E2c * 4);
    int* bsum1 = (int*)(p + o); o = align256(o + 64 * 4);
    int* bsum2 = (int*)(p + o); o = align256(o + 64 * 4);
    ushort* h    = (ushort*)(p + o); o = align256(o + (size_t)N1 * F_HID * 2);
    ushort* W1lT = (ushort*)(p + o); o = align256(o + (size_t)F_IN * F_HID * 2);
    ushort* W1rT = (ushort*)(p + o); o = align256(o + (size_t)F_IN * F_HID * 2);
    ushort* W2lT = (ushort*)(p + o); o = align256(o + (size_t)F_HID * F_OUT * 2);
    ushort* W2rT = (ushort*)(p + o); o = align256(o + (size_t)F_HID * F_OUT * 2);

    // zero both histograms with one memset (contiguous)
    hipMemsetAsync(cnt1, 0, (size_t)(N1 + N2) * 4, stream);

    // fused hist + weight transpose
    {
        int total = E1c + E2c;  // >= 2*S1 + 2*S2
        k_prep<<<(total + 255) / 256, 256, 0, stream>>>(
            ei1_dst, cnt1, ei2_dst, cnt2,
            W1l, W1r, W2l, W2r, W1lT, W1rT, W2lT, W2rT);
    }
    k_scanA2<<<NBLK1 + NBLK2, 1024, 0, stream>>>(cnt1, off1, bsum1, cnt2, off2, bsum2);
    k_scanB2<<<NBLK1 + NBLK2, 1024, 0, stream>>>(off1, cur1, bsum1, off2, cur2, bsum2);
    k_scatter2<<<(E1c + E2c + 255) / 256, 256, 0, stream>>>(
        ei1_src, ei1_dst, cur1, perm1, ei2_src, ei2_dst, cur2, perm2);

    // layer 1 fused: h = relu(mean(x[nbr]) @ W1l + x[:N1] @ W1r + b1), bf16 out
    k_sage<256, 512, 4, float, true, false><<<N1 / 32, 256, 0, stream>>>(
        x, perm1, off1, W1lT, W1rT, b1, h, nullptr);

    // layer 2 fused: out = mean(h[nbr]) @ W2l + h[:N2] @ W2r + b2, f32 out
    k_sage<128, 256, 2, ushort, false, true><<<N2 / 32, 256, 0, stream>>>(
        h, perm2, off2, W2lT, W2rT, b2, nullptr, out);
}